// Round 2
// baseline (4013.836 us; speedup 1.0000x reference)
//
#include <hip/hip_runtime.h>
#include <hip/hip_bf16.h>
#include <math.h>

// CausalAttention fused pipeline, fp32 baseline (round 2 resubmit — rounds 0/1
// never acquired a GPU; source unchanged, re-audited for correctness).
// D=1024, H=16, G=4, HD=64, T=4096, B=1.
// Stages: qkv GEMM -> l2norm+rope+transpose -> causal GQA flash attention -> out GEMM.
// All fp32 on vector ALU (no fp32 MFMA on CDNA4); bf16-split MFMA is the next
// lever pending a green baseline + tolerance probe.

#define T_SEQ 4096
#define DMODEL 1024
#define NH 16
#define NG 4
#define HD 64
#define QKV_N 1536

// ---------------- GEMM: C[M][N] = A[M][K] @ B[K][N], fp32 ----------------
// 128x128 tile, BK=8, 256 threads, 8x8 micro-tile split as {m0..m0+3, m0+64..}
// so LDS b-reads are stride-16B contiguous across lanes (conflict-free) and
// a-reads are broadcast.
__global__ __launch_bounds__(256)
void gemm_f32(const float* __restrict__ A, const float* __restrict__ B,
              float* __restrict__ C, int M, int N, int K) {
  __shared__ float a_s[8][128];
  __shared__ float b_s[8][128];
  const int tid = threadIdx.x;
  const int bm = blockIdx.y, bn = blockIdx.x;
  const int m0 = (tid >> 4) << 2;   // 0..60
  const int n0 = (tid & 15) << 2;   // 0..60
  const int arow = tid >> 1;        // 0..127
  const int acol = (tid & 1) << 2;  // 0 or 4
  const int brow = tid >> 5;        // 0..7
  const int bcol = (tid & 31) << 2; // 0..124
  const float* Ap = A + (size_t)(bm * 128 + arow) * K + acol;
  const float* Bp = B + (size_t)brow * N + bn * 128 + bcol;
  float acc[8][8];
#pragma unroll
  for (int i = 0; i < 8; i++)
#pragma unroll
    for (int j = 0; j < 8; j++) acc[i][j] = 0.f;

  for (int kt = 0; kt < K; kt += 8) {
    float4 av = *(const float4*)(Ap + kt);
    float4 bv = *(const float4*)(Bp + (size_t)kt * N);
    __syncthreads();  // previous compute done before overwrite
    a_s[acol + 0][arow] = av.x;
    a_s[acol + 1][arow] = av.y;
    a_s[acol + 2][arow] = av.z;
    a_s[acol + 3][arow] = av.w;
    *(float4*)&b_s[brow][bcol] = bv;
    __syncthreads();
#pragma unroll
    for (int kk = 0; kk < 8; kk++) {
      float af[8], bf[8];
      *(float4*)&af[0] = *(const float4*)&a_s[kk][m0];
      *(float4*)&af[4] = *(const float4*)&a_s[kk][m0 + 64];
      *(float4*)&bf[0] = *(const float4*)&b_s[kk][n0];
      *(float4*)&bf[4] = *(const float4*)&b_s[kk][n0 + 64];
#pragma unroll
      for (int i = 0; i < 8; i++)
#pragma unroll
        for (int j = 0; j < 8; j++)
          acc[i][j] = fmaf(af[i], bf[j], acc[i][j]);
    }
  }
#pragma unroll
  for (int i = 0; i < 8; i++) {
    const int row = bm * 128 + ((i < 4) ? (m0 + i) : (m0 + i - 4 + 64));
    float4 c0 = make_float4(acc[i][0], acc[i][1], acc[i][2], acc[i][3]);
    float4 c1 = make_float4(acc[i][4], acc[i][5], acc[i][6], acc[i][7]);
    *(float4*)&C[(size_t)row * N + bn * 128 + n0] = c0;
    *(float4*)&C[(size_t)row * N + bn * 128 + n0 + 64] = c1;
  }
}

// ------------- L2 norm + RoPE + transpose to head-major layouts -------------
// grid (24, 4096), 64 threads. u<16: q head u -> qT[16][T][64];
// u in 16..19: k group -> kT[4][T][64]; u in 20..23: v copy -> vT[4][T][64].
__global__ __launch_bounds__(64)
void normrope(const float* __restrict__ qkv, float* __restrict__ qT,
              float* __restrict__ kT, float* __restrict__ vT) {
  const int u = blockIdx.x;
  const int t = blockIdx.y;
  const int d = threadIdx.x;
  const float* row = qkv + (size_t)t * QKV_N;
  if (u >= 20) {
    const int g = u - 20;
    vT[(((size_t)g * T_SEQ + t) << 6) + d] = row[1280 + (g << 6) + d];
    return;
  }
  float val;
  if (u < 16) val = row[(u << 6) + d];
  else        val = row[1024 + ((u - 16) << 6) + d];
  float ss = val * val;
#pragma unroll
  for (int off = 32; off; off >>= 1) ss += __shfl_xor(ss, off);
  const float nv = val / (sqrtf(ss) + 1e-10f);
  // rope: half=32, ang = t * theta^(-(d&31)/32); out[:32]=x1*c - x2*s, out[32:]=x2*c + x1*s
  const int i = d & 31;
  const float inv_freq = powf(10000.0f, -(float)i * (1.0f / 32.0f));
  const float ang = (float)t * inv_freq;
  float sn, cs;
  sincosf(ang, &sn, &cs);
  const float partner = __shfl_xor(nv, 32);
  const float out = fmaf(nv, cs, ((d < 32) ? -partner : partner) * sn);
  if (u < 16) qT[(((size_t)u * T_SEQ + t) << 6) + d] = out;
  else        kT[(((size_t)(u - 16) * T_SEQ + t) << 6) + d] = out;
}

// ---------------- causal GQA flash attention, fp32 ----------------
// 128 threads/block = 128 query rows (one per thread), one head per block.
// K/V tiles 64x64 staged in LDS (32 KiB); all-lane broadcast reads.
// Online softmax chunked by 16 keys. Blocks issued diagonal-first.
__global__ __launch_bounds__(128)
void attn(const float* __restrict__ qT, const float* __restrict__ kT,
          const float* __restrict__ vT, float* __restrict__ att) {
  __shared__ float k_s[64][64];
  __shared__ float v_s[64][64];
  const int bx = blockIdx.x;     // 512 = 32 qtiles x 16 heads
  const int h = bx & 15;
  const int qt = 31 - (bx >> 4); // heaviest (largest q) tiles first
  const int g = h >> 2;          // kv group = h / HPG, HPG=4
  const int tid = threadIdx.x;
  const int qi = qt * 128 + tid;

  const float* qp = qT + (((size_t)h * T_SEQ + qi) << 6);
  float q[64];
#pragma unroll
  for (int i = 0; i < 16; i++) {
    float4 v4 = ((const float4*)qp)[i];
    q[4 * i] = v4.x; q[4 * i + 1] = v4.y; q[4 * i + 2] = v4.z; q[4 * i + 3] = v4.w;
  }
  float o[64];
#pragma unroll
  for (int i = 0; i < 64; i++) o[i] = 0.f;
  float m = -INFINITY, l = 0.f;

  const int ktiles = (qt << 1) + 2;
  const float4* kb = (const float4*)(kT + (((size_t)g * T_SEQ) << 6));
  const float4* vb = (const float4*)(vT + (((size_t)g * T_SEQ) << 6));

  for (int kt = 0; kt < ktiles; kt++) {
    __syncthreads();
#pragma unroll
    for (int i = 0; i < 8; i++) {
      const int idx = tid + (i << 7);  // 1024 float4s per tile
      ((float4*)k_s)[idx] = kb[(kt << 10) + idx];
      ((float4*)v_s)[idx] = vb[(kt << 10) + idx];
    }
    __syncthreads();
    const bool full = (kt * 64 + 63) <= (qt * 128);  // unmasked for all lanes
#pragma unroll 1
    for (int jc = 0; jc < 64; jc += 16) {
      float s[16];
      float cmax = -INFINITY;
#pragma unroll
      for (int j = 0; j < 16; j++) {
        const int jj = jc + j;
        const float* kr = &k_s[jj][0];
        float a0 = 0.f, a1 = 0.f, a2 = 0.f, a3 = 0.f;
#pragma unroll
        for (int i2 = 0; i2 < 16; i2++) {
          float4 kv = ((const float4*)kr)[i2];
          a0 = fmaf(q[4 * i2],     kv.x, a0);
          a1 = fmaf(q[4 * i2 + 1], kv.y, a1);
          a2 = fmaf(q[4 * i2 + 2], kv.z, a2);
          a3 = fmaf(q[4 * i2 + 3], kv.w, a3);
        }
        float sc = ((a0 + a1) + (a2 + a3)) * 0.125f;
        if (!full && (kt * 64 + jj > qi)) sc = -1e30f;  // masked; exp -> exact 0
        s[j] = sc;
        cmax = fmaxf(cmax, sc);
      }
      const float m_new = fmaxf(m, cmax);
      const float corr = __expf(m - m_new);
      l *= corr;
#pragma unroll
      for (int i = 0; i < 64; i++) o[i] *= corr;
      float psum = 0.f;
#pragma unroll
      for (int j = 0; j < 16; j++) {
        const float p = __expf(s[j] - m_new);
        psum += p;
        const float* vr = &v_s[jc + j][0];
#pragma unroll
        for (int i2 = 0; i2 < 16; i2++) {
          float4 vv = ((const float4*)vr)[i2];
          o[4 * i2]     = fmaf(p, vv.x, o[4 * i2]);
          o[4 * i2 + 1] = fmaf(p, vv.y, o[4 * i2 + 1]);
          o[4 * i2 + 2] = fmaf(p, vv.z, o[4 * i2 + 2]);
          o[4 * i2 + 3] = fmaf(p, vv.w, o[4 * i2 + 3]);
        }
      }
      l += psum;
      m = m_new;
    }
  }
  const float invl = 1.0f / l;
  float* op = att + (size_t)qi * DMODEL + (h << 6);
#pragma unroll
  for (int i = 0; i < 16; i++) {
    ((float4*)op)[i] = make_float4(o[4 * i] * invl, o[4 * i + 1] * invl,
                                   o[4 * i + 2] * invl, o[4 * i + 3] * invl);
  }
}

extern "C" void kernel_launch(void* const* d_in, const int* in_sizes, int n_in,
                              void* d_out, int out_size, void* d_ws, size_t ws_size,
                              hipStream_t stream) {
  const float* x     = (const float*)d_in[0];
  const float* w_qkv = (const float*)d_in[1];
  const float* w_o   = (const float*)d_in[2];
  float* out = (float*)d_out;

  // workspace layout (floats): total = 16,777,216 floats = 67.1 MB
  float* ws  = (float*)d_ws;
  float* qkv = ws;                                    // 4096*1536
  float* qT  = qkv + (size_t)T_SEQ * QKV_N;           // 16*4096*64
  float* kT  = qT + (size_t)NH * T_SEQ * HD;          // 4*4096*64
  float* vT  = kT + (size_t)NG * T_SEQ * HD;          // 4*4096*64
  float* att = vT + (size_t)NG * T_SEQ * HD;          // 4096*1024

  gemm_f32<<<dim3(QKV_N / 128, T_SEQ / 128), 256, 0, stream>>>(
      x, w_qkv, qkv, T_SEQ, QKV_N, DMODEL);
  normrope<<<dim3(24, T_SEQ), 64, 0, stream>>>(qkv, qT, kT, vT);
  attn<<<dim3(512), 128, 0, stream>>>(qT, kT, vT, att);
  gemm_f32<<<dim3(DMODEL / 128, T_SEQ / 128), 256, 0, stream>>>(
      att, w_o, out, T_SEQ, DMODEL, DMODEL);
}

// Round 3
// 409.908 us; speedup vs baseline: 9.7920x; 9.7920x over previous
//
#include <hip/hip_runtime.h>
#include <math.h>

// Round 3: MFMA everywhere.
// - qkv / out GEMMs: split-bf16 "emulated fp32" (hi/lo, 3 MFMAs) -> near-fp32 accuracy.
// - attention: bf16 MFMA flash attention (error damped by flat softmax, |scores|<=0.125).
// D=1024, H=16, G=4, HD=64, T=4096.

#define T_SEQ 4096
#define DMODEL 1024
#define QKV_N 1536

typedef __attribute__((ext_vector_type(8))) short s8v;   // 8 bf16 = 4 VGPRs
typedef __attribute__((ext_vector_type(4))) float f4v;   // MFMA acc

__device__ __forceinline__ unsigned short f2b(float f) {
  unsigned int b = __float_as_uint(f);
  return (unsigned short)((b + 0x7FFFu + ((b >> 16) & 1u)) >> 16);  // RNE
}
__device__ __forceinline__ float b2f(unsigned short u) {
  return __uint_as_float(((unsigned int)u) << 16);
}

// ---------- split fp32 -> (hi, lo) bf16, elementwise ----------
__global__ __launch_bounds__(256)
void split_f32(const float* __restrict__ in, unsigned short* __restrict__ hi,
               unsigned short* __restrict__ lo, int n4) {
  for (int i = blockIdx.x * 256 + threadIdx.x; i < n4; i += gridDim.x * 256) {
    float4 v = ((const float4*)in)[i];
    unsigned short h0 = f2b(v.x), h1 = f2b(v.y), h2 = f2b(v.z), h3 = f2b(v.w);
    ushort4 hv = make_ushort4(h0, h1, h2, h3);
    ushort4 lv = make_ushort4(f2b(v.x - b2f(h0)), f2b(v.y - b2f(h1)),
                              f2b(v.z - b2f(h2)), f2b(v.w - b2f(h3)));
    ((ushort4*)hi)[i] = hv;
    ((ushort4*)lo)[i] = lv;
  }
}

// ---------- transpose + split W[K][N] fp32 -> WT_hi/lo [N][K] bf16 ----------
__global__ __launch_bounds__(256)
void wsplitT(const float* __restrict__ W, unsigned short* __restrict__ WTh,
             unsigned short* __restrict__ WTl, int K, int N) {
  __shared__ float t[64][68];
  const int tid = threadIdx.x;
  const int n0 = blockIdx.x * 64, k0 = blockIdx.y * 64;
#pragma unroll
  for (int j = 0; j < 4; j++) {
    const int k = j * 16 + (tid >> 4);
    const int nn = (tid & 15) * 4;
    *(float4*)&t[k][nn] = *(const float4*)&W[(size_t)(k0 + k) * N + n0 + nn];
  }
  __syncthreads();
#pragma unroll
  for (int j = 0; j < 4; j++) {
    const int n = j * 16 + (tid >> 4);
    const int kq = (tid & 15) * 4;
    ushort4 hv, lv;
    float v0 = t[kq + 0][n], v1 = t[kq + 1][n], v2 = t[kq + 2][n], v3 = t[kq + 3][n];
    hv = make_ushort4(f2b(v0), f2b(v1), f2b(v2), f2b(v3));
    lv = make_ushort4(f2b(v0 - b2f(hv.x)), f2b(v1 - b2f(hv.y)),
                      f2b(v2 - b2f(hv.z)), f2b(v3 - b2f(hv.w)));
    *(ushort4*)&WTh[(size_t)(n0 + n) * K + k0 + kq] = hv;
    *(ushort4*)&WTl[(size_t)(n0 + n) * K + k0 + kq] = lv;
  }
}

// ---------- GEMM C[M][N] fp32 = A * B via split-bf16 MFMA ----------
// A given as Ah/Al [M][K] bf16; B as BTh/BTl [N][K] bf16 (pre-transposed).
// 128x128 tile, BK=32, 4 waves in 2x2 quadrants, 16x16x32 MFMA, 3-term split.
__global__ __launch_bounds__(256)
void gemm_split(const unsigned short* __restrict__ Ah, const unsigned short* __restrict__ Al,
                const unsigned short* __restrict__ BTh, const unsigned short* __restrict__ BTl,
                float* __restrict__ C, int M, int N, int K) {
  __shared__ unsigned short ash[2][128][40];  // [hi/lo][m][k] pad->80B rows
  __shared__ unsigned short bsh[2][128][40];  // [hi/lo][n][k]
  const int tid = threadIdx.x;
  const int lane = tid & 63, w = tid >> 6;
  const int bm = blockIdx.y, bn = blockIdx.x;
  const int ra = (w >> 1) * 64, rb = (w & 1) * 64;  // wave quadrant
  const int srow = tid >> 1, sko = (tid & 1) << 4;  // staging: 16 bf16 per thread

  const unsigned short* gAh = Ah + (size_t)(bm * 128 + srow) * K + sko;
  const unsigned short* gAl = Al + (size_t)(bm * 128 + srow) * K + sko;
  const unsigned short* gBh = BTh + (size_t)(bn * 128 + srow) * K + sko;
  const unsigned short* gBl = BTl + (size_t)(bn * 128 + srow) * K + sko;

  f4v acc[4][4];
#pragma unroll
  for (int i = 0; i < 4; i++)
#pragma unroll
    for (int j = 0; j < 4; j++) acc[i][j] = (f4v)0.f;

  const int koff = (lane >> 4) * 8;
  const int fr = lane & 15;

  for (int kt = 0; kt < K; kt += 32) {
    uint4 a0 = *(const uint4*)(gAh + kt), a1 = *(const uint4*)(gAh + kt + 8);
    uint4 l0 = *(const uint4*)(gAl + kt), l1 = *(const uint4*)(gAl + kt + 8);
    uint4 b0 = *(const uint4*)(gBh + kt), b1 = *(const uint4*)(gBh + kt + 8);
    uint4 m0 = *(const uint4*)(gBl + kt), m1 = *(const uint4*)(gBl + kt + 8);
    __syncthreads();
    *(uint4*)&ash[0][srow][sko] = a0; *(uint4*)&ash[0][srow][sko + 8] = a1;
    *(uint4*)&ash[1][srow][sko] = l0; *(uint4*)&ash[1][srow][sko + 8] = l1;
    *(uint4*)&bsh[0][srow][sko] = b0; *(uint4*)&bsh[0][srow][sko + 8] = b1;
    *(uint4*)&bsh[1][srow][sko] = m0; *(uint4*)&bsh[1][srow][sko + 8] = m1;
    __syncthreads();
    s8v ahf[4], alf[4], bhf[4], blf[4];
#pragma unroll
    for (int mi = 0; mi < 4; mi++) {
      ahf[mi] = *(const s8v*)&ash[0][ra + mi * 16 + fr][koff];
      alf[mi] = *(const s8v*)&ash[1][ra + mi * 16 + fr][koff];
    }
#pragma unroll
    for (int nj = 0; nj < 4; nj++) {
      bhf[nj] = *(const s8v*)&bsh[0][rb + nj * 16 + fr][koff];
      blf[nj] = *(const s8v*)&bsh[1][rb + nj * 16 + fr][koff];
    }
#pragma unroll
    for (int mi = 0; mi < 4; mi++)
#pragma unroll
      for (int nj = 0; nj < 4; nj++) {
        acc[mi][nj] = __builtin_amdgcn_mfma_f32_16x16x32_bf16(ahf[mi], bhf[nj], acc[mi][nj], 0, 0, 0);
        acc[mi][nj] = __builtin_amdgcn_mfma_f32_16x16x32_bf16(ahf[mi], blf[nj], acc[mi][nj], 0, 0, 0);
        acc[mi][nj] = __builtin_amdgcn_mfma_f32_16x16x32_bf16(alf[mi], bhf[nj], acc[mi][nj], 0, 0, 0);
      }
  }
  // C/D layout: col = lane&15, row = (lane>>4)*4 + r   [m89 verified]
#pragma unroll
  for (int mi = 0; mi < 4; mi++)
#pragma unroll
    for (int nj = 0; nj < 4; nj++)
#pragma unroll
      for (int r = 0; r < 4; r++) {
        const int row = bm * 128 + ra + mi * 16 + ((lane >> 4) << 2) + r;
        const int col = bn * 128 + rb + nj * 16 + fr;
        C[(size_t)row * N + col] = acc[mi][nj][r];
      }
}

// ---------- L2 norm + RoPE -> bf16 head-major layouts ----------
// qT[h][T][64] (scaled 1/8), kT[g][T][64], vTt[g][64][T] (transposed).
__global__ __launch_bounds__(64)
void normrope(const float* __restrict__ qkv, unsigned short* __restrict__ qT,
              unsigned short* __restrict__ kT, unsigned short* __restrict__ vTt) {
  const int u = blockIdx.x;
  const int t = blockIdx.y;
  const int d = threadIdx.x;
  const float* row = qkv + (size_t)t * QKV_N;
  if (u >= 20) {
    const int g = u - 20;
    vTt[((size_t)g * 64 + d) * T_SEQ + t] = f2b(row[1280 + (g << 6) + d]);
    return;
  }
  float val;
  if (u < 16) val = row[(u << 6) + d];
  else        val = row[1024 + ((u - 16) << 6) + d];
  float ss = val * val;
#pragma unroll
  for (int off = 32; off; off >>= 1) ss += __shfl_xor(ss, off);
  const float nv = val / (sqrtf(ss) + 1e-10f);
  const int i = d & 31;
  const float inv_freq = powf(10000.0f, -(float)i * (1.0f / 32.0f));
  const float ang = (float)t * inv_freq;
  float sn, cs;
  sincosf(ang, &sn, &cs);
  const float partner = __shfl_xor(nv, 32);
  const float outv = fmaf(nv, cs, ((d < 32) ? -partner : partner) * sn);
  if (u < 16) qT[((size_t)u * T_SEQ + t) * 64 + d] = f2b(outv * 0.125f);
  else        kT[((size_t)(u - 16) * T_SEQ + t) * 64 + d] = f2b(outv);
}

// ---------- causal GQA flash attention, bf16 MFMA ----------
// Block: 1 head x 128 q rows, 4 waves (32 rows each). KV tiles of 64.
// QK^T and PV via 16x16x32 MFMA; online softmax on D-fragments.
__global__ __launch_bounds__(256)
void attn(const unsigned short* __restrict__ qT, const unsigned short* __restrict__ kT,
          const unsigned short* __restrict__ vTt, float* __restrict__ att) {
  __shared__ unsigned short k_s[64][72];   // [kv][d]   144B rows, ~b128 floor
  __shared__ unsigned short v_s[64][72];   // [d][kv]
  __shared__ unsigned short p_s[128][72];  // [q][kv]
  const int bx = blockIdx.x;   // 512 = 32 qtiles x 16 heads
  const int h = bx & 15;
  const int qt = 31 - (bx >> 4);  // heavy tiles first
  const int g = h >> 2;
  const int tid = threadIdx.x;
  const int lane = tid & 63, w = tid >> 6;
  const int w32 = w * 32;
  const int rowbase = qt * 128 + w32;
  const int fr = lane & 15, fc = lane >> 4;

  // Q fragments (A-operand): row = fr, k chunk = fc*8
  s8v qf[2][2];
#pragma unroll
  for (int mi = 0; mi < 2; mi++)
#pragma unroll
    for (int kk = 0; kk < 2; kk++)
      qf[mi][kk] = *(const s8v*)(qT + ((size_t)h * T_SEQ + rowbase + mi * 16 + fr) * 64 + kk * 32 + fc * 8);

  f4v o[2][4];
#pragma unroll
  for (int mi = 0; mi < 2; mi++)
#pragma unroll
    for (int dj = 0; dj < 4; dj++) o[mi][dj] = (f4v)0.f;
  float mrow[2][4], lrow[2][4];
#pragma unroll
  for (int mi = 0; mi < 2; mi++)
#pragma unroll
    for (int r = 0; r < 4; r++) { mrow[mi][r] = -INFINITY; lrow[mi][r] = 0.f; }

  const int ktiles = 2 * qt + 2;
  const int strow = tid >> 2, stc = (tid & 3) * 16;  // staging: 32B per thread per buf

  for (int kt = 0; kt < ktiles; kt++) {
    const int kv0 = kt * 64;
    __syncthreads();
    {
      const unsigned short* kp = kT + ((size_t)g * T_SEQ + kv0 + strow) * 64 + stc;
      const unsigned short* vp = vTt + ((size_t)g * 64 + strow) * T_SEQ + kv0 + stc;
      uint4 k0 = *(const uint4*)kp, k1 = *(const uint4*)(kp + 8);
      uint4 v0 = *(const uint4*)vp, v1 = *(const uint4*)(vp + 8);
      *(uint4*)&k_s[strow][stc] = k0; *(uint4*)&k_s[strow][stc + 8] = k1;
      *(uint4*)&v_s[strow][stc] = v0; *(uint4*)&v_s[strow][stc + 8] = v1;
    }
    __syncthreads();
    const bool active = kv0 <= rowbase + 31;
    if (active) {
      // ---- QK^T ----
      f4v s[2][4];
#pragma unroll
      for (int mi = 0; mi < 2; mi++)
#pragma unroll
        for (int nj = 0; nj < 4; nj++) s[mi][nj] = (f4v)0.f;
#pragma unroll
      for (int kk = 0; kk < 2; kk++) {
        s8v kb[4];
#pragma unroll
        for (int nj = 0; nj < 4; nj++)
          kb[nj] = *(const s8v*)&k_s[nj * 16 + fr][kk * 32 + fc * 8];
#pragma unroll
        for (int mi = 0; mi < 2; mi++)
#pragma unroll
          for (int nj = 0; nj < 4; nj++)
            s[mi][nj] = __builtin_amdgcn_mfma_f32_16x16x32_bf16(qf[mi][kk], kb[nj], s[mi][nj], 0, 0, 0);
      }
      // ---- mask (diag tiles) ----
      if (kv0 + 63 > rowbase) {
#pragma unroll
        for (int mi = 0; mi < 2; mi++)
#pragma unroll
          for (int nj = 0; nj < 4; nj++)
#pragma unroll
            for (int r = 0; r < 4; r++) {
              const int rv = rowbase + mi * 16 + (fc << 2) + r;
              const int cv = kv0 + nj * 16 + fr;
              if (cv > rv) s[mi][nj][r] = -1e30f;
            }
      }
      // ---- online softmax ----
#pragma unroll
      for (int mi = 0; mi < 2; mi++) {
#pragma unroll
        for (int r = 0; r < 4; r++) {
          float tm = fmaxf(fmaxf(s[mi][0][r], s[mi][1][r]), fmaxf(s[mi][2][r], s[mi][3][r]));
          tm = fmaxf(tm, __shfl_xor(tm, 1));
          tm = fmaxf(tm, __shfl_xor(tm, 2));
          tm = fmaxf(tm, __shfl_xor(tm, 4));
          tm = fmaxf(tm, __shfl_xor(tm, 8));
          const float mnew = fmaxf(mrow[mi][r], tm);
          const float corr = __expf(mrow[mi][r] - mnew);
          mrow[mi][r] = mnew;
          lrow[mi][r] *= corr;
#pragma unroll
          for (int dj = 0; dj < 4; dj++) o[mi][dj][r] *= corr;
          float rsum = 0.f;
#pragma unroll
          for (int nj = 0; nj < 4; nj++) {
            const float p = __expf(s[mi][nj][r] - mnew);
            rsum += p;
            p_s[w32 + mi * 16 + (fc << 2) + r][nj * 16 + fr] = f2b(p);
          }
          rsum += __shfl_xor(rsum, 1);
          rsum += __shfl_xor(rsum, 2);
          rsum += __shfl_xor(rsum, 4);
          rsum += __shfl_xor(rsum, 8);
          lrow[mi][r] += rsum;
        }
      }
    }
    __syncthreads();
    if (active) {
      // ---- PV ----
#pragma unroll
      for (int kk = 0; kk < 2; kk++) {
        s8v pa[2], vb[4];
#pragma unroll
        for (int mi = 0; mi < 2; mi++)
          pa[mi] = *(const s8v*)&p_s[w32 + mi * 16 + fr][kk * 32 + fc * 8];
#pragma unroll
        for (int dj = 0; dj < 4; dj++)
          vb[dj] = *(const s8v*)&v_s[dj * 16 + fr][kk * 32 + fc * 8];
#pragma unroll
        for (int mi = 0; mi < 2; mi++)
#pragma unroll
          for (int dj = 0; dj < 4; dj++)
            o[mi][dj] = __builtin_amdgcn_mfma_f32_16x16x32_bf16(pa[mi], vb[dj], o[mi][dj], 0, 0, 0);
      }
    }
  }
  // ---- epilogue ----
#pragma unroll
  for (int mi = 0; mi < 2; mi++)
#pragma unroll
    for (int r = 0; r < 4; r++) {
      const float invl = 1.0f / lrow[mi][r];
      const int row = qt * 128 + w32 + mi * 16 + (fc << 2) + r;
#pragma unroll
      for (int dj = 0; dj < 4; dj++)
        att[(size_t)row * DMODEL + h * 64 + dj * 16 + fr] = o[mi][dj][r] * invl;
    }
}

extern "C" void kernel_launch(void* const* d_in, const int* in_sizes, int n_in,
                              void* d_out, int out_size, void* d_ws, size_t ws_size,
                              hipStream_t stream) {
  const float* x     = (const float*)d_in[0];
  const float* w_qkv = (const float*)d_in[1];
  const float* w_o   = (const float*)d_in[2];
  float* out = (float*)d_out;

  char* base = (char*)d_ws;
  // layout (bytes), total 65,011,712 < 64 MiB budget used in round 2
  float*          qkv  = (float*)(base);                    // 25165824 B (aliases att)
  float*          att  = (float*)(base);                    // 16777216 B (qkv dead by then)
  unsigned short* qT   = (unsigned short*)(base + 25165824); // 8388608
  unsigned short* kT   = (unsigned short*)(base + 33554432); // 2097152
  unsigned short* vTt  = (unsigned short*)(base + 35651584); // 2097152
  unsigned short* xh   = (unsigned short*)(base + 37748736); // 8388608 (aliases att_hi)
  unsigned short* xl   = (unsigned short*)(base + 46137344); // 8388608 (aliases att_lo)
  unsigned short* wqh  = (unsigned short*)(base + 54525952); // 3145728
  unsigned short* wql  = (unsigned short*)(base + 57671680); // 3145728
  unsigned short* woh  = (unsigned short*)(base + 60817408); // 2097152
  unsigned short* wol  = (unsigned short*)(base + 62914560); // 2097152

  wsplitT<<<dim3(QKV_N / 64, DMODEL / 64), 256, 0, stream>>>(w_qkv, wqh, wql, DMODEL, QKV_N);
  wsplitT<<<dim3(DMODEL / 64, DMODEL / 64), 256, 0, stream>>>(w_o, woh, wol, DMODEL, DMODEL);
  split_f32<<<2048, 256, 0, stream>>>(x, xh, xl, T_SEQ * DMODEL / 4);
  gemm_split<<<dim3(QKV_N / 128, T_SEQ / 128), 256, 0, stream>>>(
      xh, xl, wqh, wql, qkv, T_SEQ, QKV_N, DMODEL);
  normrope<<<dim3(24, T_SEQ), 64, 0, stream>>>(qkv, qT, kT, vTt);
  attn<<<512, 256, 0, stream>>>(qT, kT, vTt, att);
  split_f32<<<2048, 256, 0, stream>>>(att, xh, xl, T_SEQ * DMODEL / 4);
  gemm_split<<<dim3(DMODEL / 128, T_SEQ / 128), 256, 0, stream>>>(
      xh, xl, woh, wol, out, T_SEQ, DMODEL, DMODEL);
}

// Round 8
// 263.093 us; speedup vs baseline: 15.2563x; 1.5580x over previous
//
#include <hip/hip_runtime.h>
#include <math.h>

// Round 8 (= rounds 5-7 resubmit; GPU never acquired rounds 4-7. Audited 4x.)
// attn: fixed-max softmax (|s|<=0.126 bound), l via ones-MFMA, 64-row q-tiles
// longest-first, XOR-swizzled LDS, reg prefetch, split-bf16 output direct.
// GEMMs: split-bf16 3-term MFMA with reg prefetch.

#define T_SEQ 4096
#define DMODEL 1024
#define QKV_N 1536

typedef __attribute__((ext_vector_type(8))) short s8v;   // 8 bf16 = 4 VGPRs
typedef __attribute__((ext_vector_type(4))) float f4v;   // MFMA acc

__device__ __forceinline__ unsigned short f2b(float f) {
  unsigned int b = __float_as_uint(f);
  return (unsigned short)((b + 0x7FFFu + ((b >> 16) & 1u)) >> 16);  // RNE
}
__device__ __forceinline__ float b2f(unsigned short u) {
  return __uint_as_float(((unsigned int)u) << 16);
}

// ---------- split fp32 -> (hi, lo) bf16, elementwise ----------
__global__ __launch_bounds__(256)
void split_f32(const float* __restrict__ in, unsigned short* __restrict__ hi,
               unsigned short* __restrict__ lo, int n4) {
  for (int i = blockIdx.x * 256 + threadIdx.x; i < n4; i += gridDim.x * 256) {
    float4 v = ((const float4*)in)[i];
    unsigned short h0 = f2b(v.x), h1 = f2b(v.y), h2 = f2b(v.z), h3 = f2b(v.w);
    ushort4 hv = make_ushort4(h0, h1, h2, h3);
    ushort4 lv = make_ushort4(f2b(v.x - b2f(h0)), f2b(v.y - b2f(h1)),
                              f2b(v.z - b2f(h2)), f2b(v.w - b2f(h3)));
    ((ushort4*)hi)[i] = hv;
    ((ushort4*)lo)[i] = lv;
  }
}

// ---------- transpose + split W[K][N] fp32 -> WT_hi/lo [N][K] bf16 ----------
__global__ __launch_bounds__(256)
void wsplitT(const float* __restrict__ W, unsigned short* __restrict__ WTh,
             unsigned short* __restrict__ WTl, int K, int N) {
  __shared__ float t[64][68];
  const int tid = threadIdx.x;
  const int n0 = blockIdx.x * 64, k0 = blockIdx.y * 64;
#pragma unroll
  for (int j = 0; j < 4; j++) {
    const int k = j * 16 + (tid >> 4);
    const int nn = (tid & 15) * 4;
    *(float4*)&t[k][nn] = *(const float4*)&W[(size_t)(k0 + k) * N + n0 + nn];
  }
  __syncthreads();
#pragma unroll
  for (int j = 0; j < 4; j++) {
    const int n = j * 16 + (tid >> 4);
    const int kq = (tid & 15) * 4;
    ushort4 hv, lv;
    float v0 = t[kq + 0][n], v1 = t[kq + 1][n], v2 = t[kq + 2][n], v3 = t[kq + 3][n];
    hv = make_ushort4(f2b(v0), f2b(v1), f2b(v2), f2b(v3));
    lv = make_ushort4(f2b(v0 - b2f(hv.x)), f2b(v1 - b2f(hv.y)),
                      f2b(v2 - b2f(hv.z)), f2b(v3 - b2f(hv.w)));
    *(ushort4*)&WTh[(size_t)(n0 + n) * K + k0 + kq] = hv;
    *(ushort4*)&WTl[(size_t)(n0 + n) * K + k0 + kq] = lv;
  }
}

// ---------- GEMM C[M][N] fp32 = A * B via split-bf16 MFMA (prefetch dbuf) ----
__global__ __launch_bounds__(256)
void gemm_split(const unsigned short* __restrict__ Ah, const unsigned short* __restrict__ Al,
                const unsigned short* __restrict__ BTh, const unsigned short* __restrict__ BTl,
                float* __restrict__ C, int M, int N, int K) {
  __shared__ unsigned short ash[2][128][40];
  __shared__ unsigned short bsh[2][128][40];
  const int tid = threadIdx.x;
  const int lane = tid & 63, w = tid >> 6;
  const int bm = blockIdx.y, bn = blockIdx.x;
  const int ra = (w >> 1) * 64, rb = (w & 1) * 64;
  const int srow = tid >> 1, sko = (tid & 1) << 4;

  const unsigned short* gAh = Ah + (size_t)(bm * 128 + srow) * K + sko;
  const unsigned short* gAl = Al + (size_t)(bm * 128 + srow) * K + sko;
  const unsigned short* gBh = BTh + (size_t)(bn * 128 + srow) * K + sko;
  const unsigned short* gBl = BTl + (size_t)(bn * 128 + srow) * K + sko;

  f4v acc[4][4];
#pragma unroll
  for (int i = 0; i < 4; i++)
#pragma unroll
    for (int j = 0; j < 4; j++) acc[i][j] = (f4v)0.f;

  const int koff = (lane >> 4) * 8;
  const int fr = lane & 15;

  uint4 a0 = *(const uint4*)(gAh), a1 = *(const uint4*)(gAh + 8);
  uint4 l0 = *(const uint4*)(gAl), l1 = *(const uint4*)(gAl + 8);
  uint4 b0 = *(const uint4*)(gBh), b1 = *(const uint4*)(gBh + 8);
  uint4 m0 = *(const uint4*)(gBl), m1 = *(const uint4*)(gBl + 8);

  for (int kt = 0; kt < K; kt += 32) {
    __syncthreads();
    *(uint4*)&ash[0][srow][sko] = a0; *(uint4*)&ash[0][srow][sko + 8] = a1;
    *(uint4*)&ash[1][srow][sko] = l0; *(uint4*)&ash[1][srow][sko + 8] = l1;
    *(uint4*)&bsh[0][srow][sko] = b0; *(uint4*)&bsh[0][srow][sko + 8] = b1;
    *(uint4*)&bsh[1][srow][sko] = m0; *(uint4*)&bsh[1][srow][sko + 8] = m1;
    if (kt + 32 < K) {  // prefetch next K-step during compute
      const int kn = kt + 32;
      a0 = *(const uint4*)(gAh + kn); a1 = *(const uint4*)(gAh + kn + 8);
      l0 = *(const uint4*)(gAl + kn); l1 = *(const uint4*)(gAl + kn + 8);
      b0 = *(const uint4*)(gBh + kn); b1 = *(const uint4*)(gBh + kn + 8);
      m0 = *(const uint4*)(gBl + kn); m1 = *(const uint4*)(gBl + kn + 8);
    }
    __syncthreads();
    s8v ahf[4], alf[4], bhf[4], blf[4];
#pragma unroll
    for (int mi = 0; mi < 4; mi++) {
      ahf[mi] = *(const s8v*)&ash[0][ra + mi * 16 + fr][koff];
      alf[mi] = *(const s8v*)&ash[1][ra + mi * 16 + fr][koff];
    }
#pragma unroll
    for (int nj = 0; nj < 4; nj++) {
      bhf[nj] = *(const s8v*)&bsh[0][rb + nj * 16 + fr][koff];
      blf[nj] = *(const s8v*)&bsh[1][rb + nj * 16 + fr][koff];
    }
#pragma unroll
    for (int mi = 0; mi < 4; mi++)
#pragma unroll
      for (int nj = 0; nj < 4; nj++) {
        acc[mi][nj] = __builtin_amdgcn_mfma_f32_16x16x32_bf16(ahf[mi], bhf[nj], acc[mi][nj], 0, 0, 0);
        acc[mi][nj] = __builtin_amdgcn_mfma_f32_16x16x32_bf16(ahf[mi], blf[nj], acc[mi][nj], 0, 0, 0);
        acc[mi][nj] = __builtin_amdgcn_mfma_f32_16x16x32_bf16(alf[mi], bhf[nj], acc[mi][nj], 0, 0, 0);
      }
  }
#pragma unroll
  for (int mi = 0; mi < 4; mi++)
#pragma unroll
    for (int nj = 0; nj < 4; nj++)
#pragma unroll
      for (int r = 0; r < 4; r++) {
        const int row = bm * 128 + ra + mi * 16 + ((lane >> 4) << 2) + r;
        const int col = bn * 128 + rb + nj * 16 + fr;
        C[(size_t)row * N + col] = acc[mi][nj][r];
      }
}

// ---------- L2 norm + RoPE -> bf16 head-major layouts ----------
__global__ __launch_bounds__(64)
void normrope(const float* __restrict__ qkv, unsigned short* __restrict__ qT,
              unsigned short* __restrict__ kT, unsigned short* __restrict__ vTt) {
  const int u = blockIdx.x;
  const int t = blockIdx.y;
  const int d = threadIdx.x;
  const float* row = qkv + (size_t)t * QKV_N;
  if (u >= 20) {
    const int g = u - 20;
    vTt[((size_t)g * 64 + d) * T_SEQ + t] = f2b(row[1280 + (g << 6) + d]);
    return;
  }
  float val;
  if (u < 16) val = row[(u << 6) + d];
  else        val = row[1024 + ((u - 16) << 6) + d];
  float ss = val * val;
#pragma unroll
  for (int off = 32; off; off >>= 1) ss += __shfl_xor(ss, off);
  const float nv = val / (sqrtf(ss) + 1e-10f);
  const int i = d & 31;
  const float inv_freq = powf(10000.0f, -(float)i * (1.0f / 32.0f));
  const float ang = (float)t * inv_freq;
  float sn, cs;
  sincosf(ang, &sn, &cs);
  const float partner = __shfl_xor(nv, 32);
  const float outv = fmaf(nv, cs, ((d < 32) ? -partner : partner) * sn);
  if (u < 16) qT[((size_t)u * T_SEQ + t) * 64 + d] = f2b(outv * 0.125f);
  else        kT[((size_t)(u - 16) * T_SEQ + t) * 64 + d] = f2b(outv);
}

// ---------- causal GQA flash attention, bf16 MFMA, fixed-max softmax ----------
// Grid 1024 = 64 q-tiles (64 rows, longest-first) x 16 heads. 4 waves x 16 rows.
// K/V/P in XOR-swizzled [64][64] LDS (128B rows). P wave-private (no barrier
// between QK and PV). l accumulated via ones-MFMA. Split hi/lo bf16 output.
__global__ __launch_bounds__(256)
void attn(const unsigned short* __restrict__ qT, const unsigned short* __restrict__ kT,
          const unsigned short* __restrict__ vTt,
          unsigned short* __restrict__ oh, unsigned short* __restrict__ ol) {
  __shared__ unsigned short k_s[4096];
  __shared__ unsigned short v_s[4096];
  __shared__ unsigned short p_s[4096];
  const int bx = blockIdx.x;
  const int h = bx & 15;
  const int qt = 63 - (bx >> 4);   // heaviest first
  const int g = h >> 2;
  const int tid = threadIdx.x;
  const int lane = tid & 63, w = tid >> 6;
  const int fr = lane & 15, fc = lane >> 4;
  const int rswz = (fr & 7) << 3;  // fragment-read row swizzle (rows == fr mod 8)

  s8v qf[2];
  {
    const unsigned short* qp =
        qT + ((size_t)h * T_SEQ + qt * 64 + w * 16 + fr) * 64 + fc * 8;
    qf[0] = *(const s8v*)qp;
    qf[1] = *(const s8v*)(qp + 32);
  }

  f4v o[4] = {(f4v)0.f, (f4v)0.f, (f4v)0.f, (f4v)0.f};
  f4v l4 = (f4v)0.f;
  s8v ones;
#pragma unroll
  for (int i = 0; i < 8; i++) ones[i] = (short)0x3F80;  // bf16 1.0

  const int ktiles = qt + 1;
  const int strow = tid >> 2, stc = (tid & 3) << 4;
  const int sswz = (strow & 7) << 3;
  const int ks0 = strow * 64 + (stc ^ sswz);
  const int ks1 = strow * 64 + ((stc + 8) ^ sswz);
  const unsigned short* kg = kT + ((size_t)g * T_SEQ + strow) * 64 + stc;
  const unsigned short* vg = vTt + ((size_t)g * 64 + strow) * T_SEQ + stc;

  uint4 rk0 = *(const uint4*)kg, rk1 = *(const uint4*)(kg + 8);
  uint4 rv0 = *(const uint4*)vg, rv1 = *(const uint4*)(vg + 8);

  for (int kt = 0; kt < ktiles; ++kt) {
    __syncthreads();                       // prior tile fully consumed
    *(uint4*)&k_s[ks0] = rk0; *(uint4*)&k_s[ks1] = rk1;
    *(uint4*)&v_s[ks0] = rv0; *(uint4*)&v_s[ks1] = rv1;
    if (kt + 1 < ktiles) {                 // prefetch next tile during compute
      kg += 64 * 64;
      vg += 64;
      rk0 = *(const uint4*)kg; rk1 = *(const uint4*)(kg + 8);
      rv0 = *(const uint4*)vg; rv1 = *(const uint4*)(vg + 8);
    }
    __syncthreads();                       // tile kt visible

    // ---- QK^T ----
    f4v s[4] = {(f4v)0.f, (f4v)0.f, (f4v)0.f, (f4v)0.f};
#pragma unroll
    for (int kk = 0; kk < 2; kk++) {
#pragma unroll
      for (int nj = 0; nj < 4; nj++) {
        s8v kb = *(const s8v*)&k_s[(nj * 16 + fr) * 64 + ((kk * 32 + fc * 8) ^ rswz)];
        s[nj] = __builtin_amdgcn_mfma_f32_16x16x32_bf16(qf[kk], kb, s[nj], 0, 0, 0);
      }
    }
    // ---- fixed-max softmax: p = exp(s), masked -> 0; |s| <= 0.126 bounded ----
    const bool diag = (kt == qt);
#pragma unroll
    for (int nj = 0; nj < 4; nj++) {
#pragma unroll
      for (int r = 0; r < 4; r++) {
        float p = __expf(s[nj][r]);
        // causal mask within diagonal tile: kv_local > q_local (incl. wave offset w*16)
        if (diag && (nj * 16 + fr > w * 16 + fc * 4 + r)) p = 0.f;
        const int prow = w * 16 + fc * 4 + r;
        const unsigned short pb = (unsigned short)((__float_as_uint(p) + 0x8000u) >> 16);
        p_s[prow * 64 + ((nj * 16 + fr) ^ (((fc * 4 + r) & 7) << 3))] = pb;
      }
    }
    // ---- PV + row-sum via ones-MFMA (P wave-private: no barrier needed) ----
#pragma unroll
    for (int kk = 0; kk < 2; kk++) {
      s8v pa = *(const s8v*)&p_s[(w * 16 + fr) * 64 + ((kk * 32 + fc * 8) ^ rswz)];
      l4 = __builtin_amdgcn_mfma_f32_16x16x32_bf16(pa, ones, l4, 0, 0, 0);
#pragma unroll
      for (int dj = 0; dj < 4; dj++) {
        s8v vb = *(const s8v*)&v_s[(dj * 16 + fr) * 64 + ((kk * 32 + fc * 8) ^ rswz)];
        o[dj] = __builtin_amdgcn_mfma_f32_16x16x32_bf16(pa, vb, o[dj], 0, 0, 0);
      }
    }
  }
  // ---- epilogue: write split hi/lo bf16 directly (feeds out-GEMM) ----
#pragma unroll
  for (int r = 0; r < 4; r++) {
    const float invl = 1.0f / l4[r];
    const size_t row = (size_t)(qt * 64 + w * 16 + fc * 4 + r);
#pragma unroll
    for (int dj = 0; dj < 4; dj++) {
      const float val = o[dj][r] * invl;
      const unsigned short hb = f2b(val);
      const unsigned short lb = f2b(val - b2f(hb));
      const size_t idx = row * DMODEL + h * 64 + dj * 16 + fr;
      oh[idx] = hb;
      ol[idx] = lb;
    }
  }
}

extern "C" void kernel_launch(void* const* d_in, const int* in_sizes, int n_in,
                              void* d_out, int out_size, void* d_ws, size_t ws_size,
                              hipStream_t stream) {
  const float* x     = (const float*)d_in[0];
  const float* w_qkv = (const float*)d_in[1];
  const float* w_o   = (const float*)d_in[2];
  float* out = (float*)d_out;

  char* base = (char*)d_ws;
  float*          qkv  = (float*)(base);                     // 25165824 B
  unsigned short* qT   = (unsigned short*)(base + 25165824); // 8388608
  unsigned short* kT   = (unsigned short*)(base + 33554432); // 2097152
  unsigned short* vTt  = (unsigned short*)(base + 35651584); // 2097152
  unsigned short* xh   = (unsigned short*)(base + 37748736); // 8388608 (x-split, then attn-out hi)
  unsigned short* xl   = (unsigned short*)(base + 46137344); // 8388608 (x-split, then attn-out lo)
  unsigned short* wqh  = (unsigned short*)(base + 54525952); // 3145728
  unsigned short* wql  = (unsigned short*)(base + 57671680); // 3145728
  unsigned short* woh  = (unsigned short*)(base + 60817408); // 2097152
  unsigned short* wol  = (unsigned short*)(base + 62914560); // 2097152

  wsplitT<<<dim3(QKV_N / 64, DMODEL / 64), 256, 0, stream>>>(w_qkv, wqh, wql, DMODEL, QKV_N);
  wsplitT<<<dim3(DMODEL / 64, DMODEL / 64), 256, 0, stream>>>(w_o, woh, wol, DMODEL, DMODEL);
  split_f32<<<2048, 256, 0, stream>>>(x, xh, xl, T_SEQ * DMODEL / 4);
  gemm_split<<<dim3(QKV_N / 128, T_SEQ / 128), 256, 0, stream>>>(
      xh, xl, wqh, wql, qkv, T_SEQ, QKV_N, DMODEL);
  normrope<<<dim3(24, T_SEQ), 64, 0, stream>>>(qkv, qT, kT, vTt);
  attn<<<1024, 256, 0, stream>>>(qT, kT, vTt, xh, xl);  // overwrites x-split (dead)
  gemm_split<<<dim3(DMODEL / 128, T_SEQ / 128), 256, 0, stream>>>(
      xh, xl, woh, wol, out, T_SEQ, DMODEL, DMODEL);
}

// Round 13
// 209.899 us; speedup vs baseline: 19.1227x; 1.2534x over previous
//
#include <hip/hip_runtime.h>
#include <math.h>

// Round 13 (= rounds 9-12 resubmit; GPU never acquired since round 8's 263us.
// Audit budget exhausted after 6 passes; only HW can resolve fp16 absmax.)
// All-fp16 MFMA pipeline (fp32 accumulate): single-term GEMM (3x less MFMA,
// 2x less staging than split-bf16), fp16 attn P/V (reduces absmax class).
// GEMM: 64x128 tile, BK=64, reg prefetch. attn: round-8-validated structure.

#define T_SEQ 4096
#define DMODEL 1024
#define QKV_N 1536

typedef _Float16 half_t;
typedef __attribute__((ext_vector_type(8))) _Float16 h8v;  // 8 fp16 = 4 VGPRs
typedef __attribute__((ext_vector_type(4))) _Float16 h4v;
typedef __attribute__((ext_vector_type(4))) float f4v;     // MFMA acc

// ---------- cast fp32 -> fp16, 8 elems/thread ----------
__global__ __launch_bounds__(256)
void cast_f16(const float* __restrict__ in, half_t* __restrict__ out, int n8) {
  for (int i = blockIdx.x * 256 + threadIdx.x; i < n8; i += gridDim.x * 256) {
    float4 v0 = ((const float4*)in)[2 * i];
    float4 v1 = ((const float4*)in)[2 * i + 1];
    h8v h = {(half_t)v0.x, (half_t)v0.y, (half_t)v0.z, (half_t)v0.w,
             (half_t)v1.x, (half_t)v1.y, (half_t)v1.z, (half_t)v1.w};
    ((h8v*)out)[i] = h;
  }
}

// ---------- transpose + cast W[K][N] fp32 -> WT[N][K] fp16 ----------
__global__ __launch_bounds__(256)
void wcastT(const float* __restrict__ W, half_t* __restrict__ WT, int K, int N) {
  __shared__ float t[64][68];
  const int tid = threadIdx.x;
  const int n0 = blockIdx.x * 64, k0 = blockIdx.y * 64;
#pragma unroll
  for (int j = 0; j < 4; j++) {
    const int k = j * 16 + (tid >> 4);
    const int nn = (tid & 15) * 4;
    *(float4*)&t[k][nn] = *(const float4*)&W[(size_t)(k0 + k) * N + n0 + nn];
  }
  __syncthreads();
#pragma unroll
  for (int j = 0; j < 4; j++) {
    const int n = j * 16 + (tid >> 4);
    const int kq = (tid & 15) * 4;
    h4v hv = {(half_t)t[kq + 0][n], (half_t)t[kq + 1][n],
              (half_t)t[kq + 2][n], (half_t)t[kq + 3][n]};
    *(h4v*)&WT[(size_t)(n0 + n) * K + k0 + kq] = hv;
  }
}

// ---------- GEMM C[M][N] fp32 = A[M][K] * BT[N][K], fp16 MFMA ----------
// 64x128 tile, BK=64, 4 waves in 2x2 (32-row x 64-col quadrants), reg prefetch.
__global__ __launch_bounds__(256)
void gemm_f16(const half_t* __restrict__ A, const half_t* __restrict__ BT,
              float* __restrict__ C, int M, int N, int K) {
  __shared__ half_t ash[64][72];    // 144B rows (16B-aligned), ~2-way banks
  __shared__ half_t bsh[128][72];
  const int tid = threadIdx.x;
  const int lane = tid & 63, w = tid >> 6;
  const int bm = blockIdx.y, bn = blockIdx.x;
  const int ra = (w & 1) * 32, rb = (w >> 1) * 64;
  const int fr = lane & 15, fc = lane >> 4;

  const int arow = tid >> 2, ako = (tid & 3) << 4;  // 16 halfs/thread (A: 64x64)
  const int brow = tid >> 1, bko = (tid & 1) << 5;  // 32 halfs/thread (B: 128x64)

  const half_t* gA = A + (size_t)(bm * 64 + arow) * K + ako;
  const half_t* gB = BT + (size_t)(bn * 128 + brow) * K + bko;

  f4v acc[2][4];
#pragma unroll
  for (int i = 0; i < 2; i++)
#pragma unroll
    for (int j = 0; j < 4; j++) acc[i][j] = (f4v)0.f;

  uint4 pa0 = *(const uint4*)gA, pa1 = *(const uint4*)(gA + 8);
  uint4 pb0 = *(const uint4*)gB, pb1 = *(const uint4*)(gB + 8);
  uint4 pb2 = *(const uint4*)(gB + 16), pb3 = *(const uint4*)(gB + 24);

  for (int kt = 0; kt < K; kt += 64) {
    __syncthreads();
    *(uint4*)&ash[arow][ako] = pa0; *(uint4*)&ash[arow][ako + 8] = pa1;
    *(uint4*)&bsh[brow][bko] = pb0; *(uint4*)&bsh[brow][bko + 8] = pb1;
    *(uint4*)&bsh[brow][bko + 16] = pb2; *(uint4*)&bsh[brow][bko + 24] = pb3;
    if (kt + 64 < K) {  // prefetch next K-step during compute
      const int kn = kt + 64;
      pa0 = *(const uint4*)(gA + kn); pa1 = *(const uint4*)(gA + kn + 8);
      pb0 = *(const uint4*)(gB + kn); pb1 = *(const uint4*)(gB + kn + 8);
      pb2 = *(const uint4*)(gB + kn + 16); pb3 = *(const uint4*)(gB + kn + 24);
    }
    __syncthreads();
#pragma unroll
    for (int kk = 0; kk < 2; kk++) {
      const int ko = kk * 32 + fc * 8;
      h8v af[2], bf[4];
      af[0] = *(const h8v*)&ash[ra + fr][ko];
      af[1] = *(const h8v*)&ash[ra + 16 + fr][ko];
#pragma unroll
      for (int nj = 0; nj < 4; nj++)
        bf[nj] = *(const h8v*)&bsh[rb + nj * 16 + fr][ko];
#pragma unroll
      for (int mi = 0; mi < 2; mi++)
#pragma unroll
        for (int nj = 0; nj < 4; nj++)
          acc[mi][nj] = __builtin_amdgcn_mfma_f32_16x16x32_f16(af[mi], bf[nj], acc[mi][nj], 0, 0, 0);
    }
  }
  // C/D layout: col = lane&15, row = (lane>>4)*4 + r
#pragma unroll
  for (int mi = 0; mi < 2; mi++)
#pragma unroll
    for (int nj = 0; nj < 4; nj++)
#pragma unroll
      for (int r = 0; r < 4; r++) {
        const int row = bm * 64 + ra + mi * 16 + fc * 4 + r;
        const int col = bn * 128 + rb + nj * 16 + fr;
        C[(size_t)row * N + col] = acc[mi][nj][r];
      }
}

// ---------- L2 norm + RoPE -> fp16 head-major layouts ----------
__global__ __launch_bounds__(64)
void normrope(const float* __restrict__ qkv, half_t* __restrict__ qT,
              half_t* __restrict__ kT, half_t* __restrict__ vTt) {
  const int u = blockIdx.x;
  const int t = blockIdx.y;
  const int d = threadIdx.x;
  const float* row = qkv + (size_t)t * QKV_N;
  if (u >= 20) {
    const int g = u - 20;
    vTt[((size_t)g * 64 + d) * T_SEQ + t] = (half_t)row[1280 + (g << 6) + d];
    return;
  }
  float val;
  if (u < 16) val = row[(u << 6) + d];
  else        val = row[1024 + ((u - 16) << 6) + d];
  float ss = val * val;
#pragma unroll
  for (int off = 32; off; off >>= 1) ss += __shfl_xor(ss, off);
  const float nv = val / (sqrtf(ss) + 1e-10f);
  const int i = d & 31;
  const float inv_freq = powf(10000.0f, -(float)i * (1.0f / 32.0f));
  const float ang = (float)t * inv_freq;
  float sn, cs;
  sincosf(ang, &sn, &cs);
  const float partner = __shfl_xor(nv, 32);
  const float outv = fmaf(nv, cs, ((d < 32) ? -partner : partner) * sn);
  if (u < 16) qT[((size_t)u * T_SEQ + t) * 64 + d] = (half_t)(outv * 0.125f);
  else        kT[((size_t)(u - 16) * T_SEQ + t) * 64 + d] = (half_t)outv;
}

// ---------- causal GQA flash attention, fp16 MFMA, fixed-max softmax ----------
// Structure identical to round 8 (validated); operands fp16.
__global__ __launch_bounds__(256)
void attn(const half_t* __restrict__ qT, const half_t* __restrict__ kT,
          const half_t* __restrict__ vTt, half_t* __restrict__ att) {
  __shared__ half_t k_s[4096];
  __shared__ half_t v_s[4096];
  __shared__ half_t p_s[4096];
  const int bx = blockIdx.x;
  const int h = bx & 15;
  const int qt = 63 - (bx >> 4);   // heaviest first
  const int g = h >> 2;
  const int tid = threadIdx.x;
  const int lane = tid & 63, w = tid >> 6;
  const int fr = lane & 15, fc = lane >> 4;
  const int rswz = (fr & 7) << 3;  // fragment-read row swizzle (rows == fr mod 8)

  h8v qf[2];
  {
    const half_t* qp =
        qT + ((size_t)h * T_SEQ + qt * 64 + w * 16 + fr) * 64 + fc * 8;
    qf[0] = *(const h8v*)qp;
    qf[1] = *(const h8v*)(qp + 32);
  }

  f4v o[4] = {(f4v)0.f, (f4v)0.f, (f4v)0.f, (f4v)0.f};
  f4v l4 = (f4v)0.f;
  h8v ones;
#pragma unroll
  for (int i = 0; i < 8; i++) ones[i] = (half_t)1.0f;

  const int ktiles = qt + 1;
  const int strow = tid >> 2, stc = (tid & 3) << 4;
  const int sswz = (strow & 7) << 3;
  const int ks0 = strow * 64 + (stc ^ sswz);
  const int ks1 = strow * 64 + ((stc + 8) ^ sswz);
  const half_t* kg = kT + ((size_t)g * T_SEQ + strow) * 64 + stc;
  const half_t* vg = vTt + ((size_t)g * 64 + strow) * T_SEQ + stc;

  uint4 rk0 = *(const uint4*)kg, rk1 = *(const uint4*)(kg + 8);
  uint4 rv0 = *(const uint4*)vg, rv1 = *(const uint4*)(vg + 8);

  for (int kt = 0; kt < ktiles; ++kt) {
    __syncthreads();                       // prior tile fully consumed
    *(uint4*)&k_s[ks0] = rk0; *(uint4*)&k_s[ks1] = rk1;
    *(uint4*)&v_s[ks0] = rv0; *(uint4*)&v_s[ks1] = rv1;
    if (kt + 1 < ktiles) {                 // prefetch next tile during compute
      kg += 64 * 64;
      vg += 64;
      rk0 = *(const uint4*)kg; rk1 = *(const uint4*)(kg + 8);
      rv0 = *(const uint4*)vg; rv1 = *(const uint4*)(vg + 8);
    }
    __syncthreads();                       // tile kt visible

    // ---- QK^T ----
    f4v s[4] = {(f4v)0.f, (f4v)0.f, (f4v)0.f, (f4v)0.f};
#pragma unroll
    for (int kk = 0; kk < 2; kk++) {
#pragma unroll
      for (int nj = 0; nj < 4; nj++) {
        h8v kb = *(const h8v*)&k_s[(nj * 16 + fr) * 64 + ((kk * 32 + fc * 8) ^ rswz)];
        s[nj] = __builtin_amdgcn_mfma_f32_16x16x32_f16(qf[kk], kb, s[nj], 0, 0, 0);
      }
    }
    // ---- fixed-max softmax: p = exp(s); |s| <= 0.126 bounded, m == 0 ----
    const bool diag = (kt == qt);
#pragma unroll
    for (int nj = 0; nj < 4; nj++) {
#pragma unroll
      for (int r = 0; r < 4; r++) {
        float p = __expf(s[nj][r]);
        // causal mask within diagonal tile (q_local includes wave offset w*16)
        if (diag && (nj * 16 + fr > w * 16 + fc * 4 + r)) p = 0.f;
        const int prow = w * 16 + fc * 4 + r;
        p_s[prow * 64 + ((nj * 16 + fr) ^ (((fc * 4 + r) & 7) << 3))] = (half_t)p;
      }
    }
    // ---- PV + row-sum via ones-MFMA (P wave-private: no barrier needed) ----
#pragma unroll
    for (int kk = 0; kk < 2; kk++) {
      h8v pa = *(const h8v*)&p_s[(w * 16 + fr) * 64 + ((kk * 32 + fc * 8) ^ rswz)];
      l4 = __builtin_amdgcn_mfma_f32_16x16x32_f16(pa, ones, l4, 0, 0, 0);
#pragma unroll
      for (int dj = 0; dj < 4; dj++) {
        h8v vb = *(const h8v*)&v_s[(dj * 16 + fr) * 64 + ((kk * 32 + fc * 8) ^ rswz)];
        o[dj] = __builtin_amdgcn_mfma_f32_16x16x32_f16(pa, vb, o[dj], 0, 0, 0);
      }
    }
  }
  // ---- epilogue: single fp16 output (feeds out-GEMM) ----
#pragma unroll
  for (int r = 0; r < 4; r++) {
    const float invl = 1.0f / l4[r];
    const size_t row = (size_t)(qt * 64 + w * 16 + fc * 4 + r);
#pragma unroll
    for (int dj = 0; dj < 4; dj++)
      att[row * DMODEL + h * 64 + dj * 16 + fr] = (half_t)(o[dj][r] * invl);
  }
}

extern "C" void kernel_launch(void* const* d_in, const int* in_sizes, int n_in,
                              void* d_out, int out_size, void* d_ws, size_t ws_size,
                              hipStream_t stream) {
  const float* x     = (const float*)d_in[0];
  const float* w_qkv = (const float*)d_in[1];
  const float* w_o   = (const float*)d_in[2];
  float* out = (float*)d_out;

  char* base = (char*)d_ws;
  // workspace layout (bytes), total 51,380,224
  float*  qkv = (float*)(base);                    // 25165824
  half_t* qT  = (half_t*)(base + 25165824);        // 8388608
  half_t* kT  = (half_t*)(base + 33554432);        // 2097152
  half_t* vTt = (half_t*)(base + 35651584);        // 2097152
  half_t* xf  = (half_t*)(base + 37748736);        // 8388608 (x fp16, then att fp16)
  half_t* wqT = (half_t*)(base + 46137344);        // 3145728
  half_t* woT = (half_t*)(base + 49283072);        // 2097152

  wcastT<<<dim3(QKV_N / 64, DMODEL / 64), 256, 0, stream>>>(w_qkv, wqT, DMODEL, QKV_N);
  wcastT<<<dim3(DMODEL / 64, DMODEL / 64), 256, 0, stream>>>(w_o, woT, DMODEL, DMODEL);
  cast_f16<<<1024, 256, 0, stream>>>(x, xf, T_SEQ * DMODEL / 8);
  gemm_f16<<<dim3(QKV_N / 128, T_SEQ / 64), 256, 0, stream>>>(
      xf, wqT, qkv, T_SEQ, QKV_N, DMODEL);
  normrope<<<dim3(24, T_SEQ), 64, 0, stream>>>(qkv, qT, kT, vTt);
  attn<<<1024, 256, 0, stream>>>(qT, kT, vTt, xf);  // overwrites x-fp16 (dead)
  gemm_f16<<<dim3(DMODEL / 128, T_SEQ / 64), 256, 0, stream>>>(
      xf, woT, out, T_SEQ, DMODEL, DMODEL);
}